// Round 11
// baseline (4715.306 us; speedup 1.0000x reference)
//
#include <hip/hip_runtime.h>
#include <hip/hip_bf16.h>
#include <math.h>

#define N_NODES 50000
#define N_EDGES 800000
#define BN_EPS  1e-5f
#define SCAN_NB 49     // ceil(50000/1024)
#define AGG_NB  2048   // agg grid blocks

// ---- workspace layout (float-element offsets) ----
#define OFS_RELW   0
#define OFS_K      20480
#define OFS_Q      (OFS_K + 5000000)
#define OFS_V      (OFS_Q + 5000000)
#define OFS_ATTP   (OFS_V + 5000000)
#define OFS_BNPART (OFS_ATTP + 800000)          // 200 * AGG_NB
#define OFS_BNSC   (OFS_BNPART + 200 * AGG_NB)
#define OFS_BNSH   (OFS_BNSC + 128)
// int region
#define OFS_CNT    (OFS_BNSH + 128)
#define OFS_PART   (OFS_CNT + 50176)
#define OFS_BSUM   (OFS_PART + 50176)
#define OFS_OFFS   (OFS_BSUM + 64)
#define OFS_CURS   (OFS_OFFS + 50176)
#define OFS_PERM   (OFS_CURS + 50176)
#define OFS_PSRC   (OFS_PERM + 800000)
#define WS_ELEMS   (OFS_PSRC + 800000)

// rel_w[r][c] = sum_b w_comp[r][b] * relation_att[b][c]
__global__ __launch_bounds__(256) void relw_kernel(
    const float* __restrict__ wcomp, const float* __restrict__ ratt,
    float* __restrict__ relw)
{
    int o = blockIdx.x * 256 + threadIdx.x;
    if (o >= 200 * 100) return;
    int r = o / 100, c = o % 100;
    float acc = 0.f;
    #pragma unroll 10
    for (int b = 0; b < 50; ++b) acc += wcomp[r * 50 + b] * ratt[b * 100 + c];
    relw[o] = acc;
}

// fused projections: blockIdx.y = matrix m. W and X staged in LDS.
// Lane owns one output column; W column slice hoisted ONCE into VGPRs and
// PINNED with no-op asm (compiler cannot rematerialize an asm result, so
// the 100 floats stay resident; ~130 live < 256 cap from (256,2)).
// X read as wave-uniform LDS broadcasts (same-address = no conflict).
// unroll 1 on the node-group loop caps live registers (R9 lesson).
__global__ __launch_bounds__(256, 2) void proj_kernel(
    const float* __restrict__ X,
    const float* __restrict__ Wk, const float* __restrict__ bk,
    const float* __restrict__ Wq, const float* __restrict__ bq,
    const float* __restrict__ Wv, const float* __restrict__ bv,
    const float* __restrict__ Ws, const float* __restrict__ bs,
    float* __restrict__ ko, float* __restrict__ qo,
    float* __restrict__ vo, float* __restrict__ so)
{
    __shared__ float Wl[100][101];   // 40.4 KB
    __shared__ float Xs[64][100];    // 25.6 KB (66 KB total -> 2 blocks/CU)
    const int tid = threadIdx.x;
    const int nb  = blockIdx.x * 64;
    const int m   = blockIdx.y;

    const float* Wm = (m == 0) ? Wk : (m == 1) ? Wq : (m == 2) ? Wv : Ws;
    const float* bp = (m == 0) ? bk : (m == 1) ? bq : (m == 2) ? bv : bs;
    float*       op = (m == 0) ? ko : (m == 1) ? qo : (m == 2) ? vo : so;

    // stage W: 2500 float4, coalesced
    for (int idx = tid; idx < 2500; idx += 256) {
        int c_ = idx / 25, d4 = idx % 25;
        float4 w = ((const float4*)(Wm + c_ * 100))[d4];
        *(float4*)&Wl[c_][d4 * 4] = w;
    }
    // stage X tile: 1600 float4, coalesced
    for (int idx = tid; idx < 1600; idx += 256) {
        int n = idx / 25, c4 = idx % 25;
        int node = nb + n;
        float4 x = (node < N_NODES)
                   ? ((const float4*)(X + (size_t)node * 100))[c4]
                   : make_float4(0.f, 0.f, 0.f, 0.f);
        *(float4*)&Xs[n][c4 * 4] = x;
    }
    __syncthreads();

    const int wv    = tid >> 6;
    const int lane  = tid & 63;
    const int c     = (wv & 1) * 64 + lane;     // output column
    const int nhalf = (wv >> 1) * 32;           // nodes 0-31 / 32-63
    const bool act  = (c < 100);
    const int cc    = act ? c : 99;

    // hoist W column slice into VGPRs; asm pin prevents rematerialization
    float4 wreg[25];
    #pragma unroll
    for (int d4 = 0; d4 < 25; ++d4) {
        wreg[d4] = *(const float4*)&Wl[cc][d4 * 4];
        asm volatile("" : "+v"(wreg[d4].x), "+v"(wreg[d4].y),
                          "+v"(wreg[d4].z), "+v"(wreg[d4].w));
    }
    const float bias = act ? bp[c] : 0.f;

    #pragma unroll 1
    for (int nb8 = 0; nb8 < 32; nb8 += 8) {
        const int n0 = nhalf + nb8;
        float acc[8];
        #pragma unroll
        for (int j = 0; j < 8; ++j) acc[j] = 0.f;
        #pragma unroll
        for (int d4 = 0; d4 < 25; ++d4) {
            #pragma unroll
            for (int j = 0; j < 8; ++j) {
                const float4 x = *(const float4*)&Xs[n0 + j][d4 * 4]; // bcast
                acc[j] += x.x * wreg[d4].x + x.y * wreg[d4].y
                        + x.z * wreg[d4].z + x.w * wreg[d4].w;
            }
        }
        if (act) {
            #pragma unroll
            for (int j = 0; j < 8; ++j) {
                const int node = nb + n0 + j;
                if (node < N_NODES)
                    op[(size_t)node * 100 + c] = acc[j] + bias;  // coalesced
            }
        }
    }
}

__global__ __launch_bounds__(256) void hist_kernel(
    const int* __restrict__ dst, int* __restrict__ cnt)
{
    int e = blockIdx.x * 256 + threadIdx.x;
    if (e < N_EDGES) atomicAdd(&cnt[dst[e]], 1);
}

__global__ __launch_bounds__(1024) void scanA_kernel(
    const int* __restrict__ cnt, int* __restrict__ partial, int* __restrict__ bsum)
{
    __shared__ int buf[1024];
    int tid = threadIdx.x;
    int i = blockIdx.x * 1024 + tid;
    int val = (i < N_NODES) ? cnt[i] : 0;
    buf[tid] = val;
    __syncthreads();
    for (int off = 1; off < 1024; off <<= 1) {
        int t = (tid >= off) ? buf[tid - off] : 0;
        __syncthreads();
        buf[tid] += t;
        __syncthreads();
    }
    int incl = buf[tid];
    if (i < N_NODES) partial[i] = incl - val;
    if (tid == 1023) bsum[blockIdx.x] = incl;
}

__global__ __launch_bounds__(1024) void scanB_kernel(
    const int* __restrict__ partial, const int* __restrict__ bsum,
    int* __restrict__ offs)
{
    __shared__ int bs[64];
    int tid = threadIdx.x;
    if (tid < SCAN_NB) bs[tid] = bsum[tid];
    __syncthreads();
    if (tid == 0) {
        int run = 0;
        for (int b = 0; b < SCAN_NB; ++b) { int t = bs[b]; bs[b] = run; run += t; }
    }
    __syncthreads();
    for (int i = tid; i < N_NODES; i += 1024) offs[i] = partial[i] + bs[i >> 10];
    if (tid == 0) offs[N_NODES] = N_EDGES;
}

__global__ __launch_bounds__(256) void scatter_kernel(
    const int* __restrict__ src, const int* __restrict__ dst,
    const int* __restrict__ offs, int* __restrict__ cursor,
    int* __restrict__ perm, int* __restrict__ psrc)
{
    int e = blockIdx.x * 256 + threadIdx.x;
    if (e >= N_EDGES) return;
    int d = dst[e];
    int p = atomicAdd(&cursor[d], 1);
    int pos = offs[d] + p;
    perm[pos] = e;
    psrc[pos] = src[e];
}

// attention logits in CSR position order: 32 lanes/edge, float4 row loads
__global__ __launch_bounds__(256) void attp_kernel(
    const float* __restrict__ k, const float* __restrict__ q,
    const float* __restrict__ relw, const int* __restrict__ perm,
    const int* __restrict__ src, const int* __restrict__ dst,
    const int* __restrict__ etype, float* __restrict__ attp)
{
    const int lane = threadIdx.x & 31;
    const int i = blockIdx.x * 8 + (threadIdx.x >> 5);
    if (i >= N_EDGES) return;
    const int e = perm[i];
    const int s_ = src[e], d_ = dst[e], t_ = etype[e];
    float acc = 0.f;
    if (lane < 25) {
        const float4 kv = ((const float4*)(k + (size_t)s_ * 100))[lane];
        const float4 qv = ((const float4*)(q + (size_t)d_ * 100))[lane];
        const float4 wv = ((const float4*)(relw + t_ * 100))[lane];
        acc = kv.x * wv.x * qv.x + kv.y * wv.y * qv.y
            + kv.z * wv.z * qv.z + kv.w * wv.w * qv.w;
    }
    #pragma unroll
    for (int off = 16; off > 0; off >>= 1) acc += __shfl_xor(acc, off, 32);
    if (lane == 0) attp[i] = acc;
}

// one wave per node: softmax + weighted-V aggregate + gated combine + BN partials
__global__ __launch_bounds__(256) void agg_kernel(
    const int* __restrict__ offs, const int* __restrict__ psrc,
    const float* __restrict__ attp, const float* __restrict__ v,
    const float* __restrict__ alpha, float* __restrict__ out,
    float* __restrict__ bnpart)
{
    __shared__ float ls[100], lq[100];
    const int tid = threadIdx.x;
    if (tid < 100) { ls[tid] = 0.f; lq[tid] = 0.f; }
    __syncthreads();
    const int lane = tid & 63;
    const int gwave = blockIdx.x * 4 + (tid >> 6);
    const int nwaves = AGG_NB * 4;
    const float a = 1.f / (1.f + __expf(-alpha[0]));
    const float b = 1.f - a;
    const int cl = lane;            // lane owns columns 2cl, 2cl+1
    const bool act = (cl < 50);
    float sx = 0.f, sy = 0.f, qx = 0.f, qy = 0.f;

    for (int n = gwave; n < N_NODES; n += nwaves) {
        const int beg = offs[n], end = offs[n + 1];
        float m = -INFINITY;
        for (int i = beg + lane; i < end; i += 64) m = fmaxf(m, attp[i]);
        #pragma unroll
        for (int off = 32; off > 0; off >>= 1) m = fmaxf(m, __shfl_xor(m, off, 64));
        float ax = 0.f, ay = 0.f, wsum = 0.f;
        int i = beg;
        for (; i + 4 <= end; i += 4) {
            const int s0 = psrc[i], s1 = psrc[i + 1], s2 = psrc[i + 2], s3 = psrc[i + 3];
            const float w0 = __expf(attp[i] - m),     w1 = __expf(attp[i + 1] - m);
            const float w2 = __expf(attp[i + 2] - m), w3 = __expf(attp[i + 3] - m);
            wsum += w0 + w1 + w2 + w3;
            if (act) {
                const float2 x0 = ((const float2*)(v + (size_t)s0 * 100))[cl];
                const float2 x1 = ((const float2*)(v + (size_t)s1 * 100))[cl];
                const float2 x2 = ((const float2*)(v + (size_t)s2 * 100))[cl];
                const float2 x3 = ((const float2*)(v + (size_t)s3 * 100))[cl];
                ax += w0 * x0.x + w1 * x1.x + w2 * x2.x + w3 * x3.x;
                ay += w0 * x0.y + w1 * x1.y + w2 * x2.y + w3 * x3.y;
            }
        }
        for (; i < end; ++i) {
            const int s0 = psrc[i];
            const float w0 = __expf(attp[i] - m);
            wsum += w0;
            if (act) {
                const float2 x0 = ((const float2*)(v + (size_t)s0 * 100))[cl];
                ax += w0 * x0.x;
                ay += w0 * x0.y;
            }
        }
        const float inv = (wsum > 0.f) ? 1.f / wsum : 0.f;
        if (act) {
            float2* po = (float2*)(out + (size_t)n * 100);
            float2 cur = po[cl];
            float v0 = a * cur.x + b * ax * inv;
            float v1 = a * cur.y + b * ay * inv;
            po[cl] = make_float2(v0, v1);
            sx += v0; qx += v0 * v0;
            sy += v1; qy += v1 * v1;
        }
    }
    if (act) {
        atomicAdd(&ls[2 * cl], sx);     atomicAdd(&ls[2 * cl + 1], sy);
        atomicAdd(&lq[2 * cl], qx);     atomicAdd(&lq[2 * cl + 1], qy);
    }
    __syncthreads();
    if (tid < 100) {
        bnpart[(size_t)tid * AGG_NB + blockIdx.x]         = ls[tid];
        bnpart[(size_t)(tid + 100) * AGG_NB + blockIdx.x] = lq[tid];
    }
}

__global__ __launch_bounds__(256) void bnfin_kernel(
    const float* __restrict__ bnpart,
    const float* __restrict__ gamma, const float* __restrict__ beta,
    float* __restrict__ bnsc, float* __restrict__ bnsh)
{
    const int c = blockIdx.x * 4 + (threadIdx.x >> 6);
    const int lane = threadIdx.x & 63;
    if (c >= 100) return;
    float s = 0.f, q = 0.f;
    for (int b2 = lane; b2 < AGG_NB; b2 += 64) {
        s += bnpart[(size_t)c * AGG_NB + b2];
        q += bnpart[(size_t)(c + 100) * AGG_NB + b2];
    }
    #pragma unroll
    for (int off = 32; off > 0; off >>= 1) {
        s += __shfl_xor(s, off, 64);
        q += __shfl_xor(q, off, 64);
    }
    if (lane == 0) {
        const float inv_n = 1.f / (float)N_NODES;
        float mean = s * inv_n;
        float var = q * inv_n - mean * mean;
        float sc = gamma[c] * rsqrtf(var + BN_EPS);
        bnsc[c] = sc;
        bnsh[c] = beta[c] - mean * sc;
    }
}

__global__ __launch_bounds__(256) void apply_kernel(
    float* __restrict__ out, const float* __restrict__ bnsc,
    const float* __restrict__ bnsh)
{
    const int total4 = N_NODES * 25;
    for (int idx = blockIdx.x * 256 + threadIdx.x; idx < total4; idx += gridDim.x * 256) {
        float4* p = ((float4*)out) + idx;
        const int c = (idx % 25) * 4;
        float4 t = *p;
        t.x = tanhf(t.x * bnsc[c]     + bnsh[c]);
        t.y = tanhf(t.y * bnsc[c + 1] + bnsh[c + 1]);
        t.z = tanhf(t.z * bnsc[c + 2] + bnsh[c + 2]);
        t.w = tanhf(t.w * bnsc[c + 3] + bnsh[c + 3]);
        *p = t;
    }
}

__global__ __launch_bounds__(256) void rout_kernel(
    const float* __restrict__ rf, const float* __restrict__ Wr,
    const float* __restrict__ br, float* __restrict__ out)
{
    int o = blockIdx.x * 256 + threadIdx.x;
    if (o >= 200 * 100) return;
    int r = o / 100, c = o % 100;
    float acc = br[c];
    #pragma unroll 10
    for (int d = 0; d < 100; ++d) acc += rf[r * 100 + d] * Wr[c * 100 + d];
    out[N_NODES * 100 + o] = acc;
}

extern "C" void kernel_launch(void* const* d_in, const int* in_sizes, int n_in,
                              void* d_out, int out_size, void* d_ws, size_t ws_size,
                              hipStream_t stream) {
    const float* X     = (const float*)d_in[0];
    const float* rfeat = (const float*)d_in[1];
    const int*   src   = (const int*)d_in[2];
    const int*   dst   = (const int*)d_in[3];
    const int*   ety   = (const int*)d_in[4];
    const float* Wsw   = (const float*)d_in[6];
    const float* Wsb   = (const float*)d_in[7];
    const float* Wkw   = (const float*)d_in[8];
    const float* Wkb   = (const float*)d_in[9];
    const float* Wqw   = (const float*)d_in[10];
    const float* Wqb   = (const float*)d_in[11];
    const float* Wvw   = (const float*)d_in[12];
    const float* Wvb   = (const float*)d_in[13];
    const float* Wrw   = (const float*)d_in[14];
    const float* Wrb   = (const float*)d_in[15];
    const float* ratt  = (const float*)d_in[16];
    const float* wcomp = (const float*)d_in[17];
    const float* alpha = (const float*)d_in[18];
    const float* gamma = (const float*)d_in[20];
    const float* beta  = (const float*)d_in[21];

    float* out = (float*)d_out;
    float* ws  = (float*)d_ws;
    if (ws_size < (size_t)WS_ELEMS * sizeof(float)) return;

    float* relw   = ws + OFS_RELW;
    float* k      = ws + OFS_K;
    float* q      = ws + OFS_Q;
    float* v      = ws + OFS_V;
    float* attp   = ws + OFS_ATTP;
    float* bnpart = ws + OFS_BNPART;
    float* bnsc   = ws + OFS_BNSC;
    float* bnsh   = ws + OFS_BNSH;
    int* cnt      = (int*)(ws + OFS_CNT);
    int* partial  = (int*)(ws + OFS_PART);
    int* bsum     = (int*)(ws + OFS_BSUM);
    int* offs     = (int*)(ws + OFS_OFFS);
    int* cursor   = (int*)(ws + OFS_CURS);
    int* perm     = (int*)(ws + OFS_PERM);
    int* psrc     = (int*)(ws + OFS_PSRC);

    hipMemsetAsync(cnt, 0, 50000 * sizeof(int), stream);
    hipMemsetAsync(cursor, 0, 50000 * sizeof(int), stream);

    relw_kernel<<<(20000 + 255) / 256, 256, 0, stream>>>(wcomp, ratt, relw);
    proj_kernel<<<dim3((N_NODES + 63) / 64, 4), 256, 0, stream>>>(
        X, Wkw, Wkb, Wqw, Wqb, Wvw, Wvb, Wsw, Wsb, k, q, v, out);

    hist_kernel<<<(N_EDGES + 255) / 256, 256, 0, stream>>>(dst, cnt);
    scanA_kernel<<<SCAN_NB, 1024, 0, stream>>>(cnt, partial, bsum);
    scanB_kernel<<<1, 1024, 0, stream>>>(partial, bsum, offs);
    scatter_kernel<<<(N_EDGES + 255) / 256, 256, 0, stream>>>(src, dst, offs, cursor, perm, psrc);

    attp_kernel<<<(N_EDGES + 7) / 8, 256, 0, stream>>>(
        k, q, relw, perm, src, dst, ety, attp);
    agg_kernel<<<AGG_NB, 256, 0, stream>>>(offs, psrc, attp, v, alpha, out, bnpart);
    bnfin_kernel<<<25, 256, 0, stream>>>(bnpart, gamma, beta, bnsc, bnsh);
    apply_kernel<<<2048, 256, 0, stream>>>(out, bnsc, bnsh);
    rout_kernel<<<(20000 + 255) / 256, 256, 0, stream>>>(rfeat, Wrw, Wrb, out);
}

// Round 12
// 410.275 us; speedup vs baseline: 11.4930x; 11.4930x over previous
//
#include <hip/hip_runtime.h>
#include <hip/hip_bf16.h>
#include <math.h>

#define N_NODES 50000
#define N_EDGES 800000
#define BN_EPS  1e-5f
#define SCAN_NB 49     // ceil(50000/1024)
#define AGG_NB  2048   // agg grid blocks

// ---- workspace layout (float-element offsets) ----
#define OFS_RELW   0
#define OFS_K      20480
#define OFS_Q      (OFS_K + 5000000)
#define OFS_V      (OFS_Q + 5000000)
#define OFS_ATTP   (OFS_V + 5000000)
#define OFS_BNPART (OFS_ATTP + 800000)          // 200 * AGG_NB
#define OFS_BNSC   (OFS_BNPART + 200 * AGG_NB)
#define OFS_BNSH   (OFS_BNSC + 128)
// int region
#define OFS_CNT    (OFS_BNSH + 128)
#define OFS_PART   (OFS_CNT + 50176)
#define OFS_BSUM   (OFS_PART + 50176)
#define OFS_OFFS   (OFS_BSUM + 64)
#define OFS_CURS   (OFS_OFFS + 50176)
#define OFS_PERM   (OFS_CURS + 50176)
#define OFS_PSRC   (OFS_PERM + 800000)
#define WS_ELEMS   (OFS_PSRC + 800000)

// rel_w[r][c] = sum_b w_comp[r][b] * relation_att[b][c]
__global__ __launch_bounds__(256) void relw_kernel(
    const float* __restrict__ wcomp, const float* __restrict__ ratt,
    float* __restrict__ relw)
{
    int o = blockIdx.x * 256 + threadIdx.x;
    if (o >= 200 * 100) return;
    int r = o / 100, c = o % 100;
    float acc = 0.f;
    #pragma unroll 10
    for (int b = 0; b < 50; ++b) acc += wcomp[r * 50 + b] * ratt[b * 100 + c];
    relw[o] = acc;
}

// fused projections, GEMM-style: blockIdx.y = matrix m, 64-node tile.
// 512 threads = 16 node-groups x 32 col-groups (25 active); each thread
// computes a 4x4 (node x col) register tile -> acc[4][4] = 16 VGPRs only,
// no large per-lane arrays (the R8-R11 remat/spill trap is structurally
// avoided). X transposed in LDS (pad 68, 16B-aligned rows) -> one b128
// feeds 4 nodes; W row-major (pad 101) -> 4 b32 broadcast reads feed 4
// cols; 16 FMA per d-step: LDS ~35cy vs VALU 32cy per wave, balanced.
__global__ __launch_bounds__(512) void proj_kernel(
    const float* __restrict__ X,
    const float* __restrict__ Wk, const float* __restrict__ bk,
    const float* __restrict__ Wq, const float* __restrict__ bq,
    const float* __restrict__ Wv, const float* __restrict__ bv,
    const float* __restrict__ Ws, const float* __restrict__ bs,
    float* __restrict__ ko, float* __restrict__ qo,
    float* __restrict__ vo, float* __restrict__ so)
{
    __shared__ float Xt[100][68];    // transposed X tile: 27.2 KB
    __shared__ float Wl[100][101];   // row-major W:       40.4 KB (67.6 total)
    const int tid = threadIdx.x;
    const int nb  = blockIdx.x * 64;
    const int m   = blockIdx.y;

    const float* Wm = (m == 0) ? Wk : (m == 1) ? Wq : (m == 2) ? Wv : Ws;
    const float* bp = (m == 0) ? bk : (m == 1) ? bq : (m == 2) ? bv : bs;
    float*       op = (m == 0) ? ko : (m == 1) ? qo : (m == 2) ? vo : so;

    // stage W row-major: coalesced reads, conflict-free consecutive writes
    for (int idx = tid; idx < 2500; idx += 512) {
        int c_ = idx / 25, d4 = idx % 25;
        float4 w = ((const float4*)(Wm + c_ * 100))[d4];
        *(float4*)&Wl[c_][d4 * 4] = w;
    }
    // stage X transposed: coalesced float4 reads, scatter 4 b32 writes
    for (int idx = tid; idx < 1600; idx += 512) {
        int n = idx / 25, d4 = idx % 25;
        int node = nb + n;
        float4 x = (node < N_NODES)
                   ? ((const float4*)(X + (size_t)node * 100))[d4]
                   : make_float4(0.f, 0.f, 0.f, 0.f);
        Xt[d4 * 4 + 0][n] = x.x;
        Xt[d4 * 4 + 1][n] = x.y;
        Xt[d4 * 4 + 2][n] = x.z;
        Xt[d4 * 4 + 3][n] = x.w;
    }
    __syncthreads();

    const int nt  = tid & 15;        // node group: nodes nt*4 .. nt*4+3
    const int ct  = tid >> 4;        // col group 0..31 (25 active)
    const bool act = (ct < 25);
    const int cts  = act ? ct : 24;

    float acc[4][4];
    #pragma unroll
    for (int i = 0; i < 4; ++i)
        #pragma unroll
        for (int j = 0; j < 4; ++j) acc[i][j] = 0.f;

    #pragma unroll 4
    for (int d = 0; d < 100; ++d) {
        const float4 xv = *(const float4*)&Xt[d][nt * 4];
        float w0 = Wl[cts * 4 + 0][d];
        float w1 = Wl[cts * 4 + 1][d];
        float w2 = Wl[cts * 4 + 2][d];
        float w3 = Wl[cts * 4 + 3][d];
        acc[0][0] += xv.x * w0; acc[0][1] += xv.x * w1;
        acc[0][2] += xv.x * w2; acc[0][3] += xv.x * w3;
        acc[1][0] += xv.y * w0; acc[1][1] += xv.y * w1;
        acc[1][2] += xv.y * w2; acc[1][3] += xv.y * w3;
        acc[2][0] += xv.z * w0; acc[2][1] += xv.z * w1;
        acc[2][2] += xv.z * w2; acc[2][3] += xv.z * w3;
        acc[3][0] += xv.w * w0; acc[3][1] += xv.w * w1;
        acc[3][2] += xv.w * w2; acc[3][3] += xv.w * w3;
    }

    if (act) {
        const float4 bb = *(const float4*)(bp + ct * 4);
        #pragma unroll
        for (int i = 0; i < 4; ++i) {
            const int node = nb + nt * 4 + i;
            if (node < N_NODES) {
                float4 r = make_float4(acc[i][0] + bb.x, acc[i][1] + bb.y,
                                       acc[i][2] + bb.z, acc[i][3] + bb.w);
                *(float4*)(op + (size_t)node * 100 + ct * 4) = r;  // coalesced
            }
        }
    }
}

__global__ __launch_bounds__(256) void hist_kernel(
    const int* __restrict__ dst, int* __restrict__ cnt)
{
    int e = blockIdx.x * 256 + threadIdx.x;
    if (e < N_EDGES) atomicAdd(&cnt[dst[e]], 1);
}

__global__ __launch_bounds__(1024) void scanA_kernel(
    const int* __restrict__ cnt, int* __restrict__ partial, int* __restrict__ bsum)
{
    __shared__ int buf[1024];
    int tid = threadIdx.x;
    int i = blockIdx.x * 1024 + tid;
    int val = (i < N_NODES) ? cnt[i] : 0;
    buf[tid] = val;
    __syncthreads();
    for (int off = 1; off < 1024; off <<= 1) {
        int t = (tid >= off) ? buf[tid - off] : 0;
        __syncthreads();
        buf[tid] += t;
        __syncthreads();
    }
    int incl = buf[tid];
    if (i < N_NODES) partial[i] = incl - val;
    if (tid == 1023) bsum[blockIdx.x] = incl;
}

__global__ __launch_bounds__(1024) void scanB_kernel(
    const int* __restrict__ partial, const int* __restrict__ bsum,
    int* __restrict__ offs)
{
    __shared__ int bs[64];
    int tid = threadIdx.x;
    if (tid < SCAN_NB) bs[tid] = bsum[tid];
    __syncthreads();
    if (tid == 0) {
        int run = 0;
        for (int b = 0; b < SCAN_NB; ++b) { int t = bs[b]; bs[b] = run; run += t; }
    }
    __syncthreads();
    for (int i = tid; i < N_NODES; i += 1024) offs[i] = partial[i] + bs[i >> 10];
    if (tid == 0) offs[N_NODES] = N_EDGES;
}

__global__ __launch_bounds__(256) void scatter_kernel(
    const int* __restrict__ src, const int* __restrict__ dst,
    const int* __restrict__ offs, int* __restrict__ cursor,
    int* __restrict__ perm, int* __restrict__ psrc)
{
    int e = blockIdx.x * 256 + threadIdx.x;
    if (e >= N_EDGES) return;
    int d = dst[e];
    int p = atomicAdd(&cursor[d], 1);
    int pos = offs[d] + p;
    perm[pos] = e;
    psrc[pos] = src[e];
}

// attention logits in CSR position order: 32 lanes/edge, float4 row loads
__global__ __launch_bounds__(256) void attp_kernel(
    const float* __restrict__ k, const float* __restrict__ q,
    const float* __restrict__ relw, const int* __restrict__ perm,
    const int* __restrict__ src, const int* __restrict__ dst,
    const int* __restrict__ etype, float* __restrict__ attp)
{
    const int lane = threadIdx.x & 31;
    const int i = blockIdx.x * 8 + (threadIdx.x >> 5);
    if (i >= N_EDGES) return;
    const int e = perm[i];
    const int s_ = src[e], d_ = dst[e], t_ = etype[e];
    float acc = 0.f;
    if (lane < 25) {
        const float4 kv = ((const float4*)(k + (size_t)s_ * 100))[lane];
        const float4 qv = ((const float4*)(q + (size_t)d_ * 100))[lane];
        const float4 wv = ((const float4*)(relw + t_ * 100))[lane];
        acc = kv.x * wv.x * qv.x + kv.y * wv.y * qv.y
            + kv.z * wv.z * qv.z + kv.w * wv.w * qv.w;
    }
    #pragma unroll
    for (int off = 16; off > 0; off >>= 1) acc += __shfl_xor(acc, off, 32);
    if (lane == 0) attp[i] = acc;
}

// one wave per node: softmax + weighted-V aggregate + gated combine + BN partials
__global__ __launch_bounds__(256) void agg_kernel(
    const int* __restrict__ offs, const int* __restrict__ psrc,
    const float* __restrict__ attp, const float* __restrict__ v,
    const float* __restrict__ alpha, float* __restrict__ out,
    float* __restrict__ bnpart)
{
    __shared__ float ls[100], lq[100];
    const int tid = threadIdx.x;
    if (tid < 100) { ls[tid] = 0.f; lq[tid] = 0.f; }
    __syncthreads();
    const int lane = tid & 63;
    const int gwave = blockIdx.x * 4 + (tid >> 6);
    const int nwaves = AGG_NB * 4;
    const float a = 1.f / (1.f + __expf(-alpha[0]));
    const float b = 1.f - a;
    const int cl = lane;            // lane owns columns 2cl, 2cl+1
    const bool act = (cl < 50);
    float sx = 0.f, sy = 0.f, qx = 0.f, qy = 0.f;

    for (int n = gwave; n < N_NODES; n += nwaves) {
        const int beg = offs[n], end = offs[n + 1];
        float m = -INFINITY;
        for (int i = beg + lane; i < end; i += 64) m = fmaxf(m, attp[i]);
        #pragma unroll
        for (int off = 32; off > 0; off >>= 1) m = fmaxf(m, __shfl_xor(m, off, 64));
        float ax = 0.f, ay = 0.f, wsum = 0.f;
        int i = beg;
        for (; i + 4 <= end; i += 4) {
            const int s0 = psrc[i], s1 = psrc[i + 1], s2 = psrc[i + 2], s3 = psrc[i + 3];
            const float w0 = __expf(attp[i] - m),     w1 = __expf(attp[i + 1] - m);
            const float w2 = __expf(attp[i + 2] - m), w3 = __expf(attp[i + 3] - m);
            wsum += w0 + w1 + w2 + w3;
            if (act) {
                const float2 x0 = ((const float2*)(v + (size_t)s0 * 100))[cl];
                const float2 x1 = ((const float2*)(v + (size_t)s1 * 100))[cl];
                const float2 x2 = ((const float2*)(v + (size_t)s2 * 100))[cl];
                const float2 x3 = ((const float2*)(v + (size_t)s3 * 100))[cl];
                ax += w0 * x0.x + w1 * x1.x + w2 * x2.x + w3 * x3.x;
                ay += w0 * x0.y + w1 * x1.y + w2 * x2.y + w3 * x3.y;
            }
        }
        for (; i < end; ++i) {
            const int s0 = psrc[i];
            const float w0 = __expf(attp[i] - m);
            wsum += w0;
            if (act) {
                const float2 x0 = ((const float2*)(v + (size_t)s0 * 100))[cl];
                ax += w0 * x0.x;
                ay += w0 * x0.y;
            }
        }
        const float inv = (wsum > 0.f) ? 1.f / wsum : 0.f;
        if (act) {
            float2* po = (float2*)(out + (size_t)n * 100);
            float2 cur = po[cl];
            float v0 = a * cur.x + b * ax * inv;
            float v1 = a * cur.y + b * ay * inv;
            po[cl] = make_float2(v0, v1);
            sx += v0; qx += v0 * v0;
            sy += v1; qy += v1 * v1;
        }
    }
    if (act) {
        atomicAdd(&ls[2 * cl], sx);     atomicAdd(&ls[2 * cl + 1], sy);
        atomicAdd(&lq[2 * cl], qx);     atomicAdd(&lq[2 * cl + 1], qy);
    }
    __syncthreads();
    if (tid < 100) {
        bnpart[(size_t)tid * AGG_NB + blockIdx.x]         = ls[tid];
        bnpart[(size_t)(tid + 100) * AGG_NB + blockIdx.x] = lq[tid];
    }
}

__global__ __launch_bounds__(256) void bnfin_kernel(
    const float* __restrict__ bnpart,
    const float* __restrict__ gamma, const float* __restrict__ beta,
    float* __restrict__ bnsc, float* __restrict__ bnsh)
{
    const int c = blockIdx.x * 4 + (threadIdx.x >> 6);
    const int lane = threadIdx.x & 63;
    if (c >= 100) return;
    float s = 0.f, q = 0.f;
    for (int b2 = lane; b2 < AGG_NB; b2 += 64) {
        s += bnpart[(size_t)c * AGG_NB + b2];
        q += bnpart[(size_t)(c + 100) * AGG_NB + b2];
    }
    #pragma unroll
    for (int off = 32; off > 0; off >>= 1) {
        s += __shfl_xor(s, off, 64);
        q += __shfl_xor(q, off, 64);
    }
    if (lane == 0) {
        const float inv_n = 1.f / (float)N_NODES;
        float mean = s * inv_n;
        float var = q * inv_n - mean * mean;
        float sc = gamma[c] * rsqrtf(var + BN_EPS);
        bnsc[c] = sc;
        bnsh[c] = beta[c] - mean * sc;
    }
}

__global__ __launch_bounds__(256) void apply_kernel(
    float* __restrict__ out, const float* __restrict__ bnsc,
    const float* __restrict__ bnsh)
{
    const int total4 = N_NODES * 25;
    for (int idx = blockIdx.x * 256 + threadIdx.x; idx < total4; idx += gridDim.x * 256) {
        float4* p = ((float4*)out) + idx;
        const int c = (idx % 25) * 4;
        float4 t = *p;
        t.x = tanhf(t.x * bnsc[c]     + bnsh[c]);
        t.y = tanhf(t.y * bnsc[c + 1] + bnsh[c + 1]);
        t.z = tanhf(t.z * bnsc[c + 2] + bnsh[c + 2]);
        t.w = tanhf(t.w * bnsc[c + 3] + bnsh[c + 3]);
        *p = t;
    }
}

__global__ __launch_bounds__(256) void rout_kernel(
    const float* __restrict__ rf, const float* __restrict__ Wr,
    const float* __restrict__ br, float* __restrict__ out)
{
    int o = blockIdx.x * 256 + threadIdx.x;
    if (o >= 200 * 100) return;
    int r = o / 100, c = o % 100;
    float acc = br[c];
    #pragma unroll 10
    for (int d = 0; d < 100; ++d) acc += rf[r * 100 + d] * Wr[c * 100 + d];
    out[N_NODES * 100 + o] = acc;
}

extern "C" void kernel_launch(void* const* d_in, const int* in_sizes, int n_in,
                              void* d_out, int out_size, void* d_ws, size_t ws_size,
                              hipStream_t stream) {
    const float* X     = (const float*)d_in[0];
    const float* rfeat = (const float*)d_in[1];
    const int*   src   = (const int*)d_in[2];
    const int*   dst   = (const int*)d_in[3];
    const int*   ety   = (const int*)d_in[4];
    const float* Wsw   = (const float*)d_in[6];
    const float* Wsb   = (const float*)d_in[7];
    const float* Wkw   = (const float*)d_in[8];
    const float* Wkb   = (const float*)d_in[9];
    const float* Wqw   = (const float*)d_in[10];
    const float* Wqb   = (const float*)d_in[11];
    const float* Wvw   = (const float*)d_in[12];
    const float* Wvb   = (const float*)d_in[13];
    const float* Wrw   = (const float*)d_in[14];
    const float* Wrb   = (const float*)d_in[15];
    const float* ratt  = (const float*)d_in[16];
    const float* wcomp = (const float*)d_in[17];
    const float* alpha = (const float*)d_in[18];
    const float* gamma = (const float*)d_in[20];
    const float* beta  = (const float*)d_in[21];

    float* out = (float*)d_out;
    float* ws  = (float*)d_ws;
    if (ws_size < (size_t)WS_ELEMS * sizeof(float)) return;

    float* relw   = ws + OFS_RELW;
    float* k      = ws + OFS_K;
    float* q      = ws + OFS_Q;
    float* v      = ws + OFS_V;
    float* attp   = ws + OFS_ATTP;
    float* bnpart = ws + OFS_BNPART;
    float* bnsc   = ws + OFS_BNSC;
    float* bnsh   = ws + OFS_BNSH;
    int* cnt      = (int*)(ws + OFS_CNT);
    int* partial  = (int*)(ws + OFS_PART);
    int* bsum     = (int*)(ws + OFS_BSUM);
    int* offs     = (int*)(ws + OFS_OFFS);
    int* cursor   = (int*)(ws + OFS_CURS);
    int* perm     = (int*)(ws + OFS_PERM);
    int* psrc     = (int*)(ws + OFS_PSRC);

    hipMemsetAsync(cnt, 0, 50000 * sizeof(int), stream);
    hipMemsetAsync(cursor, 0, 50000 * sizeof(int), stream);

    relw_kernel<<<(20000 + 255) / 256, 256, 0, stream>>>(wcomp, ratt, relw);
    proj_kernel<<<dim3((N_NODES + 63) / 64, 4), 512, 0, stream>>>(
        X, Wkw, Wkb, Wqw, Wqb, Wvw, Wvb, Wsw, Wsb, k, q, v, out);

    hist_kernel<<<(N_EDGES + 255) / 256, 256, 0, stream>>>(dst, cnt);
    scanA_kernel<<<SCAN_NB, 1024, 0, stream>>>(cnt, partial, bsum);
    scanB_kernel<<<1, 1024, 0, stream>>>(partial, bsum, offs);
    scatter_kernel<<<(N_EDGES + 255) / 256, 256, 0, stream>>>(src, dst, offs, cursor, perm, psrc);

    attp_kernel<<<(N_EDGES + 7) / 8, 256, 0, stream>>>(
        k, q, relw, perm, src, dst, ety, attp);
    agg_kernel<<<AGG_NB, 256, 0, stream>>>(offs, psrc, attp, v, alpha, out, bnpart);
    bnfin_kernel<<<25, 256, 0, stream>>>(bnpart, gamma, beta, bnsc, bnsh);
    apply_kernel<<<2048, 256, 0, stream>>>(out, bnsc, bnsh);
    rout_kernel<<<(20000 + 255) / 256, 256, 0, stream>>>(rfeat, Wrw, Wrb, out);
}

// Round 13
// 370.969 us; speedup vs baseline: 12.7108x; 1.1060x over previous
//
#include <hip/hip_runtime.h>
#include <hip/hip_bf16.h>
#include <math.h>

#define N_NODES 50000
#define N_EDGES 800000
#define BN_EPS  1e-5f
#define SCAN_NB 49     // ceil(50000/1024)
#define AGG_NB  2048   // agg grid blocks

// ---- workspace layout (float-element offsets) ----
#define OFS_RELW   0
#define OFS_KH     20480                         // 50000*128 ushort = 3.2M floats
#define OFS_Q      (OFS_KH + 5000000)
#define OFS_VH     (OFS_Q + 5000000)             // 50000*128 ushort
#define OFS_ATTP   (OFS_VH + 5000000)
#define OFS_BNPART (OFS_ATTP + 800000)           // 200 * AGG_NB
#define OFS_BNSC   (OFS_BNPART + 200 * AGG_NB)
#define OFS_BNSH   (OFS_BNSC + 128)
// int region
#define OFS_CNT    (OFS_BNSH + 128)
#define OFS_PART   (OFS_CNT + 50176)
#define OFS_BSUM   (OFS_PART + 50176)
#define OFS_OFFS   (OFS_BSUM + 64)
#define OFS_CURS   (OFS_OFFS + 50176)
#define OFS_PERM   (OFS_CURS + 50176)
#define OFS_PSRC   (OFS_PERM + 800000)
#define WS_ELEMS   (OFS_PSRC + 800000)

__device__ __forceinline__ unsigned short f2bf(float f) {   // RNE float->bf16
    unsigned u = __float_as_uint(f);
    return (unsigned short)((u + 0x7FFFu + ((u >> 16) & 1u)) >> 16);
}
__device__ __forceinline__ float bf2f(unsigned short h) {
    return __uint_as_float((unsigned)h << 16);
}

// rel_w[r][c] = sum_b w_comp[r][b] * relation_att[b][c]
__global__ __launch_bounds__(256) void relw_kernel(
    const float* __restrict__ wcomp, const float* __restrict__ ratt,
    float* __restrict__ relw)
{
    int o = blockIdx.x * 256 + threadIdx.x;
    if (o >= 200 * 100) return;
    int r = o / 100, c = o % 100;
    float acc = 0.f;
    #pragma unroll 10
    for (int b = 0; b < 50; ++b) acc += wcomp[r * 50 + b] * ratt[b * 100 + c];
    relw[o] = acc;
}

// fused projections, GEMM-style 4x4 register tile (R12 structure).
// m=0 (k) and m=2 (v) are written ONLY as bf16, rows padded to 128 elems
// (256B = 4 aligned cache lines) -> halves the random-gather traffic in
// attp/agg. m=1 (q) and m=3 (s) stay fp32.
__global__ __launch_bounds__(512) void proj_kernel(
    const float* __restrict__ X,
    const float* __restrict__ Wk, const float* __restrict__ bk,
    const float* __restrict__ Wq, const float* __restrict__ bq,
    const float* __restrict__ Wv, const float* __restrict__ bv,
    const float* __restrict__ Ws, const float* __restrict__ bs,
    unsigned short* __restrict__ kh, float* __restrict__ qo,
    unsigned short* __restrict__ vh, float* __restrict__ so)
{
    __shared__ float Xt[100][68];    // transposed X tile: 27.2 KB
    __shared__ float Wl[100][101];   // row-major W:       40.4 KB
    const int tid = threadIdx.x;
    const int nb  = blockIdx.x * 64;
    const int m   = blockIdx.y;

    const float* Wm = (m == 0) ? Wk : (m == 1) ? Wq : (m == 2) ? Wv : Ws;
    const float* bp = (m == 0) ? bk : (m == 1) ? bq : (m == 2) ? bv : bs;

    for (int idx = tid; idx < 2500; idx += 512) {
        int c_ = idx / 25, d4 = idx % 25;
        float4 w = ((const float4*)(Wm + c_ * 100))[d4];
        *(float4*)&Wl[c_][d4 * 4] = w;
    }
    for (int idx = tid; idx < 1600; idx += 512) {
        int n = idx / 25, d4 = idx % 25;
        int node = nb + n;
        float4 x = (node < N_NODES)
                   ? ((const float4*)(X + (size_t)node * 100))[d4]
                   : make_float4(0.f, 0.f, 0.f, 0.f);
        Xt[d4 * 4 + 0][n] = x.x;
        Xt[d4 * 4 + 1][n] = x.y;
        Xt[d4 * 4 + 2][n] = x.z;
        Xt[d4 * 4 + 3][n] = x.w;
    }
    __syncthreads();

    const int nt  = tid & 15;
    const int ct  = tid >> 4;
    const bool act = (ct < 25);
    const int cts  = act ? ct : 24;

    float acc[4][4];
    #pragma unroll
    for (int i = 0; i < 4; ++i)
        #pragma unroll
        for (int j = 0; j < 4; ++j) acc[i][j] = 0.f;

    #pragma unroll 4
    for (int d = 0; d < 100; ++d) {
        const float4 xv = *(const float4*)&Xt[d][nt * 4];
        float w0 = Wl[cts * 4 + 0][d];
        float w1 = Wl[cts * 4 + 1][d];
        float w2 = Wl[cts * 4 + 2][d];
        float w3 = Wl[cts * 4 + 3][d];
        acc[0][0] += xv.x * w0; acc[0][1] += xv.x * w1;
        acc[0][2] += xv.x * w2; acc[0][3] += xv.x * w3;
        acc[1][0] += xv.y * w0; acc[1][1] += xv.y * w1;
        acc[1][2] += xv.y * w2; acc[1][3] += xv.y * w3;
        acc[2][0] += xv.z * w0; acc[2][1] += xv.z * w1;
        acc[2][2] += xv.z * w2; acc[2][3] += xv.z * w3;
        acc[3][0] += xv.w * w0; acc[3][1] += xv.w * w1;
        acc[3][2] += xv.w * w2; acc[3][3] += xv.w * w3;
    }

    if (act) {
        const float4 bb = *(const float4*)(bp + ct * 4);
        if (m == 0 || m == 2) {
            unsigned short* oph = (m == 0) ? kh : vh;
            #pragma unroll
            for (int i = 0; i < 4; ++i) {
                const int node = nb + nt * 4 + i;
                if (node < N_NODES) {
                    ushort4 hh;
                    hh.x = f2bf(acc[i][0] + bb.x);
                    hh.y = f2bf(acc[i][1] + bb.y);
                    hh.z = f2bf(acc[i][2] + bb.z);
                    hh.w = f2bf(acc[i][3] + bb.w);
                    *(ushort4*)(oph + (size_t)node * 128 + ct * 4) = hh;
                }
            }
        } else {
            float* opf = (m == 1) ? qo : so;
            #pragma unroll
            for (int i = 0; i < 4; ++i) {
                const int node = nb + nt * 4 + i;
                if (node < N_NODES) {
                    float4 r = make_float4(acc[i][0] + bb.x, acc[i][1] + bb.y,
                                           acc[i][2] + bb.z, acc[i][3] + bb.w);
                    *(float4*)(opf + (size_t)node * 100 + ct * 4) = r;
                }
            }
        }
    }
}

__global__ __launch_bounds__(256) void hist_kernel(
    const int* __restrict__ dst, int* __restrict__ cnt)
{
    int e = blockIdx.x * 256 + threadIdx.x;
    if (e < N_EDGES) atomicAdd(&cnt[dst[e]], 1);
}

__global__ __launch_bounds__(1024) void scanA_kernel(
    const int* __restrict__ cnt, int* __restrict__ partial, int* __restrict__ bsum)
{
    __shared__ int buf[1024];
    int tid = threadIdx.x;
    int i = blockIdx.x * 1024 + tid;
    int val = (i < N_NODES) ? cnt[i] : 0;
    buf[tid] = val;
    __syncthreads();
    for (int off = 1; off < 1024; off <<= 1) {
        int t = (tid >= off) ? buf[tid - off] : 0;
        __syncthreads();
        buf[tid] += t;
        __syncthreads();
    }
    int incl = buf[tid];
    if (i < N_NODES) partial[i] = incl - val;
    if (tid == 1023) bsum[blockIdx.x] = incl;
}

__global__ __launch_bounds__(1024) void scanB_kernel(
    const int* __restrict__ partial, const int* __restrict__ bsum,
    int* __restrict__ offs)
{
    __shared__ int bs[64];
    int tid = threadIdx.x;
    if (tid < SCAN_NB) bs[tid] = bsum[tid];
    __syncthreads();
    if (tid == 0) {
        int run = 0;
        for (int b = 0; b < SCAN_NB; ++b) { int t = bs[b]; bs[b] = run; run += t; }
    }
    __syncthreads();
    for (int i = tid; i < N_NODES; i += 1024) offs[i] = partial[i] + bs[i >> 10];
    if (tid == 0) offs[N_NODES] = N_EDGES;
}

__global__ __launch_bounds__(256) void scatter_kernel(
    const int* __restrict__ src, const int* __restrict__ dst,
    const int* __restrict__ offs, int* __restrict__ cursor,
    int* __restrict__ perm, int* __restrict__ psrc)
{
    int e = blockIdx.x * 256 + threadIdx.x;
    if (e >= N_EDGES) return;
    int d = dst[e];
    int p = atomicAdd(&cursor[d], 1);
    int pos = offs[d] + p;
    perm[pos] = e;
    psrc[pos] = src[e];
}

// attention logits in CSR position order: 32 lanes/edge; k gathered as bf16
// (256B aligned rows), q fp32 (dst-sorted -> L1), relw fp32 (L2-resident).
__global__ __launch_bounds__(256) void attp_kernel(
    const unsigned short* __restrict__ kh, const float* __restrict__ q,
    const float* __restrict__ relw, const int* __restrict__ perm,
    const int* __restrict__ src, const int* __restrict__ dst,
    const int* __restrict__ etype, float* __restrict__ attp)
{
    const int lane = threadIdx.x & 31;
    const int i = blockIdx.x * 8 + (threadIdx.x >> 5);
    if (i >= N_EDGES) return;
    const int e = perm[i];
    const int s_ = src[e], d_ = dst[e], t_ = etype[e];
    float acc = 0.f;
    if (lane < 25) {
        const ushort4 kt = ((const ushort4*)(kh + (size_t)s_ * 128))[lane];
        const float4 qv = ((const float4*)(q + (size_t)d_ * 100))[lane];
        const float4 wv = ((const float4*)(relw + t_ * 100))[lane];
        acc = bf2f(kt.x) * wv.x * qv.x + bf2f(kt.y) * wv.y * qv.y
            + bf2f(kt.z) * wv.z * qv.z + bf2f(kt.w) * wv.w * qv.w;
    }
    #pragma unroll
    for (int off = 16; off > 0; off >>= 1) acc += __shfl_xor(acc, off, 32);
    if (lane == 0) attp[i] = acc;
}

// one wave per node: softmax + weighted-V aggregate (v gathered as bf16)
// + gated combine + BN partials
__global__ __launch_bounds__(256) void agg_kernel(
    const int* __restrict__ offs, const int* __restrict__ psrc,
    const float* __restrict__ attp, const unsigned short* __restrict__ vh,
    const float* __restrict__ alpha, float* __restrict__ out,
    float* __restrict__ bnpart)
{
    __shared__ float ls[100], lq[100];
    const int tid = threadIdx.x;
    if (tid < 100) { ls[tid] = 0.f; lq[tid] = 0.f; }
    __syncthreads();
    const int lane = tid & 63;
    const int gwave = blockIdx.x * 4 + (tid >> 6);
    const int nwaves = AGG_NB * 4;
    const float a = 1.f / (1.f + __expf(-alpha[0]));
    const float b = 1.f - a;
    const int cl = lane;            // lane owns columns 2cl, 2cl+1
    const bool act = (cl < 50);
    float sx = 0.f, sy = 0.f, qx = 0.f, qy = 0.f;

    for (int n = gwave; n < N_NODES; n += nwaves) {
        const int beg = offs[n], end = offs[n + 1];
        float m = -INFINITY;
        for (int i = beg + lane; i < end; i += 64) m = fmaxf(m, attp[i]);
        #pragma unroll
        for (int off = 32; off > 0; off >>= 1) m = fmaxf(m, __shfl_xor(m, off, 64));
        float ax = 0.f, ay = 0.f, wsum = 0.f;
        int i = beg;
        for (; i + 4 <= end; i += 4) {
            const int s0 = psrc[i], s1 = psrc[i + 1], s2 = psrc[i + 2], s3 = psrc[i + 3];
            const float w0 = __expf(attp[i] - m),     w1 = __expf(attp[i + 1] - m);
            const float w2 = __expf(attp[i + 2] - m), w3 = __expf(attp[i + 3] - m);
            wsum += w0 + w1 + w2 + w3;
            if (act) {
                const unsigned h0 = ((const unsigned*)(vh + (size_t)s0 * 128))[cl];
                const unsigned h1 = ((const unsigned*)(vh + (size_t)s1 * 128))[cl];
                const unsigned h2 = ((const unsigned*)(vh + (size_t)s2 * 128))[cl];
                const unsigned h3 = ((const unsigned*)(vh + (size_t)s3 * 128))[cl];
                ax += w0 * bf2f((unsigned short)(h0 & 0xFFFFu))
                    + w1 * bf2f((unsigned short)(h1 & 0xFFFFu))
                    + w2 * bf2f((unsigned short)(h2 & 0xFFFFu))
                    + w3 * bf2f((unsigned short)(h3 & 0xFFFFu));
                ay += w0 * bf2f((unsigned short)(h0 >> 16))
                    + w1 * bf2f((unsigned short)(h1 >> 16))
                    + w2 * bf2f((unsigned short)(h2 >> 16))
                    + w3 * bf2f((unsigned short)(h3 >> 16));
            }
        }
        for (; i < end; ++i) {
            const int s0 = psrc[i];
            const float w0 = __expf(attp[i] - m);
            wsum += w0;
            if (act) {
                const unsigned h0 = ((const unsigned*)(vh + (size_t)s0 * 128))[cl];
                ax += w0 * bf2f((unsigned short)(h0 & 0xFFFFu));
                ay += w0 * bf2f((unsigned short)(h0 >> 16));
            }
        }
        const float inv = (wsum > 0.f) ? 1.f / wsum : 0.f;
        if (act) {
            float2* po = (float2*)(out + (size_t)n * 100);
            float2 cur = po[cl];
            float v0 = a * cur.x + b * ax * inv;
            float v1 = a * cur.y + b * ay * inv;
            po[cl] = make_float2(v0, v1);
            sx += v0; qx += v0 * v0;
            sy += v1; qy += v1 * v1;
        }
    }
    if (act) {
        atomicAdd(&ls[2 * cl], sx);     atomicAdd(&ls[2 * cl + 1], sy);
        atomicAdd(&lq[2 * cl], qx);     atomicAdd(&lq[2 * cl + 1], qy);
    }
    __syncthreads();
    if (tid < 100) {
        bnpart[(size_t)tid * AGG_NB + blockIdx.x]         = ls[tid];
        bnpart[(size_t)(tid + 100) * AGG_NB + blockIdx.x] = lq[tid];
    }
}

__global__ __launch_bounds__(256) void bnfin_kernel(
    const float* __restrict__ bnpart,
    const float* __restrict__ gamma, const float* __restrict__ beta,
    float* __restrict__ bnsc, float* __restrict__ bnsh)
{
    const int c = blockIdx.x * 4 + (threadIdx.x >> 6);
    const int lane = threadIdx.x & 63;
    if (c >= 100) return;
    float s = 0.f, q = 0.f;
    for (int b2 = lane; b2 < AGG_NB; b2 += 64) {
        s += bnpart[(size_t)c * AGG_NB + b2];
        q += bnpart[(size_t)(c + 100) * AGG_NB + b2];
    }
    #pragma unroll
    for (int off = 32; off > 0; off >>= 1) {
        s += __shfl_xor(s, off, 64);
        q += __shfl_xor(q, off, 64);
    }
    if (lane == 0) {
        const float inv_n = 1.f / (float)N_NODES;
        float mean = s * inv_n;
        float var = q * inv_n - mean * mean;
        float sc = gamma[c] * rsqrtf(var + BN_EPS);
        bnsc[c] = sc;
        bnsh[c] = beta[c] - mean * sc;
    }
}

__global__ __launch_bounds__(256) void apply_kernel(
    float* __restrict__ out, const float* __restrict__ bnsc,
    const float* __restrict__ bnsh)
{
    const int total4 = N_NODES * 25;
    for (int idx = blockIdx.x * 256 + threadIdx.x; idx < total4; idx += gridDim.x * 256) {
        float4* p = ((float4*)out) + idx;
        const int c = (idx % 25) * 4;
        float4 t = *p;
        t.x = tanhf(t.x * bnsc[c]     + bnsh[c]);
        t.y = tanhf(t.y * bnsc[c + 1] + bnsh[c + 1]);
        t.z = tanhf(t.z * bnsc[c + 2] + bnsh[c + 2]);
        t.w = tanhf(t.w * bnsc[c + 3] + bnsh[c + 3]);
        *p = t;
    }
}

__global__ __launch_bounds__(256) void rout_kernel(
    const float* __restrict__ rf, const float* __restrict__ Wr,
    const float* __restrict__ br, float* __restrict__ out)
{
    int o = blockIdx.x * 256 + threadIdx.x;
    if (o >= 200 * 100) return;
    int r = o / 100, c = o % 100;
    float acc = br[c];
    #pragma unroll 10
    for (int d = 0; d < 100; ++d) acc += rf[r * 100 + d] * Wr[c * 100 + d];
    out[N_NODES * 100 + o] = acc;
}

extern "C" void kernel_launch(void* const* d_in, const int* in_sizes, int n_in,
                              void* d_out, int out_size, void* d_ws, size_t ws_size,
                              hipStream_t stream) {
    const float* X     = (const float*)d_in[0];
    const float* rfeat = (const float*)d_in[1];
    const int*   src   = (const int*)d_in[2];
    const int*   dst   = (const int*)d_in[3];
    const int*   ety   = (const int*)d_in[4];
    const float* Wsw   = (const float*)d_in[6];
    const float* Wsb   = (const float*)d_in[7];
    const float* Wkw   = (const float*)d_in[8];
    const float* Wkb   = (const float*)d_in[9];
    const float* Wqw   = (const float*)d_in[10];
    const float* Wqb   = (const float*)d_in[11];
    const float* Wvw   = (const float*)d_in[12];
    const float* Wvb   = (const float*)d_in[13];
    const float* Wrw   = (const float*)d_in[14];
    const float* Wrb   = (const float*)d_in[15];
    const float* ratt  = (const float*)d_in[16];
    const float* wcomp = (const float*)d_in[17];
    const float* alpha = (const float*)d_in[18];
    const float* gamma = (const float*)d_in[20];
    const float* beta  = (const float*)d_in[21];

    float* out = (float*)d_out;
    float* ws  = (float*)d_ws;
    if (ws_size < (size_t)WS_ELEMS * sizeof(float)) return;

    float* relw            = ws + OFS_RELW;
    unsigned short* kh     = (unsigned short*)(ws + OFS_KH);
    float* q               = ws + OFS_Q;
    unsigned short* vh     = (unsigned short*)(ws + OFS_VH);
    float* attp            = ws + OFS_ATTP;
    float* bnpart          = ws + OFS_BNPART;
    float* bnsc            = ws + OFS_BNSC;
    float* bnsh            = ws + OFS_BNSH;
    int* cnt               = (int*)(ws + OFS_CNT);
    int* partial           = (int*)(ws + OFS_PART);
    int* bsum              = (int*)(ws + OFS_BSUM);
    int* offs              = (int*)(ws + OFS_OFFS);
    int* cursor            = (int*)(ws + OFS_CURS);
    int* perm              = (int*)(ws + OFS_PERM);
    int* psrc              = (int*)(ws + OFS_PSRC);

    hipMemsetAsync(cnt, 0, 50000 * sizeof(int), stream);
    hipMemsetAsync(cursor, 0, 50000 * sizeof(int), stream);

    relw_kernel<<<(20000 + 255) / 256, 256, 0, stream>>>(wcomp, ratt, relw);
    proj_kernel<<<dim3((N_NODES + 63) / 64, 4), 512, 0, stream>>>(
        X, Wkw, Wkb, Wqw, Wqb, Wvw, Wvb, Wsw, Wsb, kh, q, vh, out);

    hist_kernel<<<(N_EDGES + 255) / 256, 256, 0, stream>>>(dst, cnt);
    scanA_kernel<<<SCAN_NB, 1024, 0, stream>>>(cnt, partial, bsum);
    scanB_kernel<<<1, 1024, 0, stream>>>(partial, bsum, offs);
    scatter_kernel<<<(N_EDGES + 255) / 256, 256, 0, stream>>>(src, dst, offs, cursor, perm, psrc);

    attp_kernel<<<(N_EDGES + 7) / 8, 256, 0, stream>>>(
        kh, q, relw, perm, src, dst, ety, attp);
    agg_kernel<<<AGG_NB, 256, 0, stream>>>(offs, psrc, attp, vh, alpha, out, bnpart);
    bnfin_kernel<<<25, 256, 0, stream>>>(bnpart, gamma, beta, bnsc, bnsh);
    apply_kernel<<<2048, 256, 0, stream>>>(out, bnsc, bnsh);
    rout_kernel<<<(20000 + 255) / 256, 256, 0, stream>>>(rfeat, Wrw, Wrb, out);
}